// Round 17
// baseline (42.842 us; speedup 1.0000x reference)
//
#include <hip/hip_runtime.h>

// CubeLens: radial lens deflection + bilinear gather + 4x4 avg pool.
// C=64, NS=256, NL=192, UPS=4. Output (64,192,192) fp32.
//
// R17: LDS BOX STAGING. Evidence: R16 (4x loads) = +30%, R12 (uncoalesced)
// = +70%, R13/R14 (barrier/VGPR changes) = 0 -> scattered gather loads are
// the cost. Fix: dedup across the block's 32 pixels. Union of their 4x4
// patches fits a fixed 24x8-corner box (~typical span 11x3) -> stage box
// ONCE (24KB, 6 contiguous f16x8 loads/thread), gather from LDS.
//   1A: tap geometry -> Btap; per-pixel patch base/mode; block box via
//       LDS atomicMin/Max over mode-1 patch bases.
//   stage(T14): issue 6 box loads -> regs; 1B weights while in flight;
//       ds_write box (x-stride padded 144B -> no pixel-alias conflicts).
//   2:  boxed mode-1 px: 16 ds_read_b128 (static offsets) + FMA.
//       non-boxed / mode-2 px: per-tap global gather (general path).
//   epilogue: LDS repack -> nontemporal f32x4 stores. XCD swizzle.
//   k1: fp32->fp16 channel-last transpose (unchanged, ~3.5us w/ launch).

#define NSRC 256
#define NLENS 192
#define NPIX (NLENS * NLENS)     // 36864
#define CSZ  64
#define PXB  32                  // pixels per block
#define NBLK (NPIX / PXB)        // 1152, divisible by 8
#define NTTILE (NSRC * NSRC / 64)
#define BW   24                  // box width in corners
#define BH   8                   // box height in corners
#define XSTR 72                  // halfs per x step (64 + 8 pad: bank shift)
#define RSTR (BW * XSTR)         // 1728 halfs per box row

typedef float    f32x4 __attribute__((ext_vector_type(4)));
typedef _Float16 f16x8 __attribute__((ext_vector_type(8)));

// ---------------- fallback (round-1 kernel, used only if ws too small) ------
__global__ __launch_bounds__(256) void cubelens_fallback(
    const float* __restrict__ src, const float* __restrict__ theta_p,
    float* __restrict__ out)
{
    const float tE = theta_p[0];
    const int pix = blockIdx.x * 256 + threadIdx.x;
    const int c0  = blockIdx.y * 8;
    const int lx  = pix % NLENS;
    const int ly  = pix / NLENS;
    float acc[8];
#pragma unroll
    for (int c = 0; c < 8; ++c) acc[c] = 0.0f;
    const float* __restrict__ srcg = src + (size_t)c0 * (NSRC * NSRC);
#pragma unroll
    for (int uy = 0; uy < 4; ++uy) {
        const float thy = ((float)(ly * 4 + uy) - 383.5f) * 0.01f;
#pragma unroll
        for (int ux = 0; ux < 4; ++ux) {
            const float thx = ((float)(lx * 4 + ux) - 383.5f) * 0.01f;
            const float r  = sqrtf(thx * thx + thy * thy) + 1e-8f;
            const float fx = (thx - (tE * thx) / r) / 0.02f + 127.5f;
            const float fy = (thy - (tE * thy) / r) / 0.02f + 127.5f;
            const bool inb = (fx >= 0.0f) & (fx <= 255.0f) &
                             (fy >= 0.0f) & (fy <= 255.0f);
            if (!inb) continue;
            int x0 = min(max((int)floorf(fx), 0), 254);
            int y0 = min(max((int)floorf(fy), 0), 254);
            const float wx = fminf(fmaxf(fx - (float)x0, 0.0f), 1.0f);
            const float wy = fminf(fmaxf(fy - (float)y0, 0.0f), 1.0f);
            const float w00 = (1.0f - wy) * (1.0f - wx);
            const float w01 = (1.0f - wy) * wx;
            const float w10 = wy * (1.0f - wx);
            const float w11 = wy * wx;
            const float* __restrict__ p = srcg + y0 * NSRC + x0;
#pragma unroll
            for (int c = 0; c < 8; ++c) {
                const float* __restrict__ pc = p + c * (NSRC * NSRC);
                acc[c] += w00 * pc[0] + w01 * pc[1]
                        + w10 * pc[NSRC] + w11 * pc[NSRC + 1];
            }
        }
    }
#pragma unroll
    for (int c = 0; c < 8; ++c)
        out[(size_t)(c0 + c) * NPIX + pix] = acc[c] * 0.0625f;
}

// ---------------- k1: transpose (c,p) fp32 -> (p,c) fp16, XCD swizzle -------
__global__ __launch_bounds__(256) void transpose_kernel(
    const float* __restrict__ src, _Float16* __restrict__ ws)
{
    __shared__ float tile[CSZ][65];
    const int b = blockIdx.x;
    const int tileid = (b & 7) * (NTTILE / 8) + (b >> 3);
    const int p0 = tileid * 64;
    const int t  = threadIdx.x;
    {
        const int crow = t >> 4;
        const int px4  = (t & 15) * 4;
#pragma unroll
        for (int i = 0; i < 4; ++i) {
            const int c = crow + 16 * i;
            const f32x4 v = __builtin_nontemporal_load(
                (const f32x4*)(src + (size_t)c * (NSRC * NSRC) + p0 + px4));
            tile[c][px4 + 0] = v.x; tile[c][px4 + 1] = v.y;
            tile[c][px4 + 2] = v.z; tile[c][px4 + 3] = v.w;
        }
    }
    __syncthreads();
    {
        const int c8 = (t & 7) * 8;
        const int pr = t >> 3;
#pragma unroll
        for (int i = 0; i < 2; ++i) {
            const int p = pr + 32 * i;
            f16x8 h;
#pragma unroll
            for (int k = 0; k < 8; ++k) h[k] = (_Float16)tile[c8 + k][p];
            *(f16x8*)(ws + (size_t)(p0 + p) * CSZ + c8) = h;
        }
    }
}

// ---------------- k2: lens gather with LDS box staging ----------------------
struct Tap { int x0, y0; float wx, wy; bool inb; };

__device__ __forceinline__ Tap tapgeom(int p, int sub, float tE) {
    const int lx = p % NLENS, ly = p / NLENS;
    const float thy = ((float)(ly * 4 + (sub >> 2)) - 383.5f) * 0.01f;
    const float thx = ((float)(lx * 4 + (sub & 3))  - 383.5f) * 0.01f;
    const float r  = sqrtf(thx * thx + thy * thy) + 1e-8f;
    const float fx = (thx - (tE * thx) / r) / 0.02f + 127.5f;
    const float fy = (thy - (tE * thy) / r) / 0.02f + 127.5f;
    Tap tp;
    tp.inb = (fx >= 0.0f) & (fx <= 255.0f) & (fy >= 0.0f) & (fy <= 255.0f);
    tp.x0 = min(max((int)floorf(fx), 0), 254);
    tp.y0 = min(max((int)floorf(fy), 0), 254);
    tp.wx = fminf(fmaxf(fx - (float)tp.x0, 0.0f), 1.0f);
    tp.wy = fminf(fmaxf(fy - (float)tp.y0, 0.0f), 1.0f);
    return tp;
}

__global__ __launch_bounds__(256, 4) void cubelens_main(
    const _Float16* __restrict__ ws,    // (256,256,64) fp16
    const float* __restrict__ theta_p,
    float* __restrict__ out)            // (64,192,192) fp32
{
    __shared__ _Float16 box[BH * RSTR];                       // 27648 B
    __shared__ union {
        f32x4 Btap[PXB][16];                                  // 8192 B
        float smemO[CSZ][PXB + 1];                            // 8448 B
    } u;
    __shared__ float wpatch[PXB][16];
    __shared__ int   gmode[PXB];
    __shared__ int   pbx[PXB], pby[PXB];
    __shared__ int   bminx, bminy, bmaxx, bmaxy;

    const float tE = theta_p[0];
    const int b = blockIdx.x;
    const int pixblock = (b & 7) * (NBLK / 8) + (b >> 3);     // XCD swizzle
    const int p0 = pixblock * PXB;
    const int t  = threadIdx.x;

    if (t == 0) {
        bminx = 1 << 30; bminy = 1 << 30;
        bmaxx = -(1 << 30); bmaxy = -(1 << 30);
    }
    __syncthreads();

    // ---- 1A: tap geometry + per-pixel patch base/mode + block box ----
    {
        const int g = t >> 4, sub = t & 15;
#pragma unroll
        for (int h = 0; h < 2; ++h) {
            const int pi = 2 * g + h;
            const Tap tp = tapgeom(p0 + pi, sub, tE);
            const float x0f = (float)tp.x0, y0f = (float)tp.y0;
            float mnx = tp.inb ? x0f : 1e9f;
            float mny = tp.inb ? y0f : 1e9f;
#pragma unroll
            for (int off = 1; off < 16; off <<= 1) {
                mnx = fminf(mnx, __shfl_xor(mnx, off, 16));
                mny = fminf(mny, __shfl_xor(mny, off, 16));
            }
            const bool allout = (mnx > 5e8f);
            int viol = (tp.inb & ((x0f > mnx + 2.0f) | (y0f > mny + 2.0f))) ? 1 : 0;
#pragma unroll
            for (int off = 1; off < 16; off <<= 1)
                viol |= __shfl_xor(viol, off, 16);
            const float bxc = fminf(mnx, 252.0f);
            const float byc = fminf(mny, 252.0f);
            f32x4 rec;
            rec.x = tp.inb ? (x0f - bxc) : -1000.0f;
            rec.y = tp.inb ? (y0f - byc) : -1000.0f;
            rec.z = tp.wx;
            rec.w = tp.wy;
            u.Btap[pi][sub] = rec;
            if (sub == 0) {
                const int md = allout ? 0 : (viol ? 2 : 1);
                gmode[pi] = md;
                pbx[pi] = (int)bxc; pby[pi] = (int)byc;
                if (md == 1) {
                    atomicMin(&bminx, (int)bxc); atomicMax(&bmaxx, (int)bxc);
                    atomicMin(&bminy, (int)byc); atomicMax(&bmaxy, (int)byc);
                }
            }
        }
    }
    __syncthreads();

    const bool boxed = (bmaxx >= bminx) &&
                       (bmaxx - bminx <= NSRC - BW - 232 + 20) && // = 20
                       (bmaxy - bminy <= 4);
    const int bx0 = min(bminx, NSRC - BW);   // <= 232
    const int by0 = min(bminy, NSRC - BH);   // <= 248

    // ---- T14 issue-early: 6 contiguous box-row loads per thread ----
    f16x8 stg[6];
    if (boxed) {
#pragma unroll
        for (int k = 0; k < 6; ++k) {
            const int ci  = k * 256 + t;            // 0..1535
            const int row = ci / 192;               // const-div
            const int rem = ci - row * 192;
            stg[k] = *(const f16x8*)
                (ws + ((size_t)(by0 + row) * NSRC + bx0) * CSZ + rem * 8);
        }
    }

    // ---- 1B: corner weights while staging loads fly ----
    if (boxed) {
        const int sub = t & 15;
        const float cxf = (float)(sub & 3), cyf = (float)(sub >> 2);
#pragma unroll
        for (int h = 0; h < 2; ++h) {
            const int pi = (t >> 4) + 16 * h;
            float myw = 0.0f;
#pragma unroll
            for (int j = 0; j < 16; ++j) {
                const f32x4 r = u.Btap[pi][j];
                const float tx = cxf - r.x;
                const float ty = cyf - r.y;
                const float wxp = (tx == 0.0f) ? (1.0f - r.z)
                                : ((tx == 1.0f) ? r.z : 0.0f);
                const float wyp = (ty == 0.0f) ? (1.0f - r.w)
                                : ((ty == 1.0f) ? r.w : 0.0f);
                myw += wxp * wyp;
            }
            wpatch[pi][sub] = myw * 0.0625f;
        }
        // write staged box (padded x-stride: 144B -> 4-bank shift per x)
#pragma unroll
        for (int k = 0; k < 6; ++k) {
            const int ci  = k * 256 + t;
            const int row = ci / 192;
            const int rem = ci - row * 192;
            const int x = rem >> 3, cg = rem & 7;
            *(f16x8*)(box + row * RSTR + x * XSTR + cg * 8) = stg[k];
        }
    }
    __syncthreads();

    // ---- phase 2: gather. thread = (pixel, c8) ----
    {
        const int pi2 = t >> 3, c8 = t & 7;
        const int md = gmode[pi2];
        float acc[8];
#pragma unroll
        for (int e = 0; e < 8; ++e) acc[e] = 0.0f;

        if (boxed && md == 1) {
            const _Float16* __restrict__ lb =
                box + (pby[pi2] - by0) * RSTR + (pbx[pi2] - bx0) * XSTR + c8 * 8;
#pragma unroll
            for (int half = 0; half < 2; ++half) {
                f16x8 v[8];
                float w[8];
#pragma unroll
                for (int k = 0; k < 8; ++k) {
                    const int cn = half * 8 + k;
                    v[k] = *(const f16x8*)(lb + (cn >> 2) * RSTR + (cn & 3) * XSTR);
                    w[k] = wpatch[pi2][cn];
                }
#pragma unroll
                for (int k = 0; k < 8; ++k)
#pragma unroll
                    for (int e = 0; e < 8; ++e)
                        acc[e] += w[k] * (float)v[k][e];
            }
        } else if (md != 0) {
            // general per-tap global path (non-boxed blocks & mode-2 px)
            for (int tap = 0; tap < 16; ++tap) {
                const Tap tp = tapgeom(p0 + pi2, tap, tE);
                if (tp.inb) {
                    const _Float16* __restrict__ pp =
                        ws + ((size_t)tp.y0 * NSRC + tp.x0) * CSZ + c8 * 8;
                    const f16x8 v00 = *(const f16x8*)(pp);
                    const f16x8 v01 = *(const f16x8*)(pp + CSZ);
                    const f16x8 v10 = *(const f16x8*)(pp + NSRC * CSZ);
                    const f16x8 v11 = *(const f16x8*)(pp + NSRC * CSZ + CSZ);
                    const float w00 = (1.0f - tp.wy) * (1.0f - tp.wx);
                    const float w01 = (1.0f - tp.wy) * tp.wx;
                    const float w10 = tp.wy * (1.0f - tp.wx);
                    const float w11 = tp.wy * tp.wx;
#pragma unroll
                    for (int e = 0; e < 8; ++e)
                        acc[e] += w00 * (float)v00[e] + w01 * (float)v01[e]
                                + w10 * (float)v10[e] + w11 * (float)v11[e];
                }
            }
#pragma unroll
            for (int e = 0; e < 8; ++e) acc[e] *= 0.0625f;
        }

        __syncthreads();   // Btap dead; safe to reuse union as smemO
#pragma unroll
        for (int e = 0; e < 8; ++e) u.smemO[c8 * 8 + e][pi2] = acc[e];
    }
    __syncthreads();

    // ---- epilogue: coalesced nontemporal f32x4 stores ----
    {
        const int c   = t >> 2;
        const int px8 = (t & 3) * 8;
        float* op = out + (size_t)c * NPIX + p0 + px8;
        f32x4 v0, v1;
        v0.x = u.smemO[c][px8 + 0]; v0.y = u.smemO[c][px8 + 1];
        v0.z = u.smemO[c][px8 + 2]; v0.w = u.smemO[c][px8 + 3];
        v1.x = u.smemO[c][px8 + 4]; v1.y = u.smemO[c][px8 + 5];
        v1.z = u.smemO[c][px8 + 6]; v1.w = u.smemO[c][px8 + 7];
        __builtin_nontemporal_store(v0, (f32x4*)op);
        __builtin_nontemporal_store(v1, (f32x4*)(op + 4));
    }
}

extern "C" void kernel_launch(void* const* d_in, const int* in_sizes, int n_in,
                              void* d_out, int out_size, void* d_ws, size_t ws_size,
                              hipStream_t stream) {
    const float* src   = (const float*)d_in[0];
    const float* theta = (const float*)d_in[1];
    float* out = (float*)d_out;

    const size_t need = (size_t)CSZ * NSRC * NSRC * sizeof(_Float16);  // 8.4 MB
    if (ws_size >= need) {
        _Float16* ws = (_Float16*)d_ws;
        transpose_kernel<<<dim3(NTTILE), dim3(256), 0, stream>>>(src, ws);
        cubelens_main<<<dim3(NBLK), dim3(256), 0, stream>>>(ws, theta, out);
    } else {
        cubelens_fallback<<<dim3(NPIX / 256, 8), dim3(256), 0, stream>>>(src, theta, out);
    }
}

// Round 18
// 34.060 us; speedup vs baseline: 1.2578x; 1.2578x over previous
//
#include <hip/hip_runtime.h>

// CubeLens: radial lens deflection + bilinear gather + 4x4 avg pool.
// C=64, NS=256, NL=192, UPS=4. Output (64,192,192) fp32.
//
// R18: TABLE-DRIVEN GATHER AT FULL OCCUPANCY.
// Evidence ledger: loads x4 -> +30% (R16); uncoalesced -> +70% (R12);
// sync restructures -> 0 (R13/R14); T+o=3.5us (R15); M~26us with no pipe
// >11% busy => ~216 cy per wave-load = exposed latency. All prior mains
// held v[16]+geometry+shfl -> >64 VGPR -> 4 waves/SIMD (occupancy steps
// at 64/128/256). Fix: split M.
//   k2 weights: R14's 1A/1B machinery -> global tables
//       tbase[p] (>=0: patch base | -1: all-out | -2: wide-span),
//       tw[p][16] fp32 (pre-scaled 1/16), trec[p][16] (mode-2 taps).
//   k3 gather: table read + 2x8 batched f16x8 corner loads + FMA +
//       LDS repack. No geometry, no shfl, no Btap -> <=64 VGPR target
//       via __launch_bounds__(256,8) -> 8 waves/SIMD = 2x MLP.
//   k1 transpose: unchanged.

#define NSRC 256
#define NLENS 192
#define NPIX (NLENS * NLENS)     // 36864
#define CSZ  64
#define PXB  32                  // pixels per block
#define NBLK (NPIX / PXB)        // 1152, divisible by 8
#define NTTILE (NSRC * NSRC / 64)

#define WS0_BYTES  (NSRC * NSRC * CSZ * 2)           // 8388608  fp16 cube
#define TB_OFF     WS0_BYTES                          // tbase: NPIX int
#define TW_OFF     (TB_OFF + NPIX * 4)                // tw: NPIX*16 f32
#define TR_OFF     (TW_OFF + NPIX * 16 * 4)           // trec: NPIX*16 int4
#define WS_TOTAL   (TR_OFF + NPIX * 16 * 16)

typedef float    f32x4 __attribute__((ext_vector_type(4)));
typedef _Float16 f16x8 __attribute__((ext_vector_type(8)));

// ---------------- fallback (round-1 kernel, used only if ws too small) ------
__global__ __launch_bounds__(256) void cubelens_fallback(
    const float* __restrict__ src, const float* __restrict__ theta_p,
    float* __restrict__ out)
{
    const float tE = theta_p[0];
    const int pix = blockIdx.x * 256 + threadIdx.x;
    const int c0  = blockIdx.y * 8;
    const int lx  = pix % NLENS;
    const int ly  = pix / NLENS;
    float acc[8];
#pragma unroll
    for (int c = 0; c < 8; ++c) acc[c] = 0.0f;
    const float* __restrict__ srcg = src + (size_t)c0 * (NSRC * NSRC);
#pragma unroll
    for (int uy = 0; uy < 4; ++uy) {
        const float thy = ((float)(ly * 4 + uy) - 383.5f) * 0.01f;
#pragma unroll
        for (int ux = 0; ux < 4; ++ux) {
            const float thx = ((float)(lx * 4 + ux) - 383.5f) * 0.01f;
            const float r  = sqrtf(thx * thx + thy * thy) + 1e-8f;
            const float fx = (thx - (tE * thx) / r) / 0.02f + 127.5f;
            const float fy = (thy - (tE * thy) / r) / 0.02f + 127.5f;
            const bool inb = (fx >= 0.0f) & (fx <= 255.0f) &
                             (fy >= 0.0f) & (fy <= 255.0f);
            if (!inb) continue;
            int x0 = min(max((int)floorf(fx), 0), 254);
            int y0 = min(max((int)floorf(fy), 0), 254);
            const float wx = fminf(fmaxf(fx - (float)x0, 0.0f), 1.0f);
            const float wy = fminf(fmaxf(fy - (float)y0, 0.0f), 1.0f);
            const float w00 = (1.0f - wy) * (1.0f - wx);
            const float w01 = (1.0f - wy) * wx;
            const float w10 = wy * (1.0f - wx);
            const float w11 = wy * wx;
            const float* __restrict__ p = srcg + y0 * NSRC + x0;
#pragma unroll
            for (int c = 0; c < 8; ++c) {
                const float* __restrict__ pc = p + c * (NSRC * NSRC);
                acc[c] += w00 * pc[0] + w01 * pc[1]
                        + w10 * pc[NSRC] + w11 * pc[NSRC + 1];
            }
        }
    }
#pragma unroll
    for (int c = 0; c < 8; ++c)
        out[(size_t)(c0 + c) * NPIX + pix] = acc[c] * 0.0625f;
}

// ---------------- k1: transpose (c,p) fp32 -> (p,c) fp16, XCD swizzle -------
__global__ __launch_bounds__(256) void transpose_kernel(
    const float* __restrict__ src, _Float16* __restrict__ ws)
{
    __shared__ float tile[CSZ][65];
    const int b = blockIdx.x;
    const int tileid = (b & 7) * (NTTILE / 8) + (b >> 3);
    const int p0 = tileid * 64;
    const int t  = threadIdx.x;
    {
        const int crow = t >> 4;
        const int px4  = (t & 15) * 4;
#pragma unroll
        for (int i = 0; i < 4; ++i) {
            const int c = crow + 16 * i;
            const f32x4 v = __builtin_nontemporal_load(
                (const f32x4*)(src + (size_t)c * (NSRC * NSRC) + p0 + px4));
            tile[c][px4 + 0] = v.x; tile[c][px4 + 1] = v.y;
            tile[c][px4 + 2] = v.z; tile[c][px4 + 3] = v.w;
        }
    }
    __syncthreads();
    {
        const int c8 = (t & 7) * 8;
        const int pr = t >> 3;
#pragma unroll
        for (int i = 0; i < 2; ++i) {
            const int p = pr + 32 * i;
            f16x8 h;
#pragma unroll
            for (int k = 0; k < 8; ++k) h[k] = (_Float16)tile[c8 + k][p];
            *(f16x8*)(ws + (size_t)(p0 + p) * CSZ + c8) = h;
        }
    }
}

// ---------------- k2: weights table builder ---------------------------------
struct Tap { int x0, y0; float wx, wy; bool inb; };

__device__ __forceinline__ Tap tapgeom(int p, int sub, float tE) {
    const int lx = p % NLENS, ly = p / NLENS;
    const float thy = ((float)(ly * 4 + (sub >> 2)) - 383.5f) * 0.01f;
    const float thx = ((float)(lx * 4 + (sub & 3))  - 383.5f) * 0.01f;
    const float r  = sqrtf(thx * thx + thy * thy) + 1e-8f;
    const float fx = (thx - (tE * thx) / r) / 0.02f + 127.5f;
    const float fy = (thy - (tE * thy) / r) / 0.02f + 127.5f;
    Tap tp;
    tp.inb = (fx >= 0.0f) & (fx <= 255.0f) & (fy >= 0.0f) & (fy <= 255.0f);
    tp.x0 = min(max((int)floorf(fx), 0), 254);
    tp.y0 = min(max((int)floorf(fy), 0), 254);
    tp.wx = fminf(fmaxf(fx - (float)tp.x0, 0.0f), 1.0f);
    tp.wy = fminf(fmaxf(fy - (float)tp.y0, 0.0f), 1.0f);
    return tp;
}

__global__ __launch_bounds__(256, 4) void cubelens_weights(
    const float* __restrict__ theta_p,
    int*  __restrict__ tbase,           // [NPIX]
    float* __restrict__ tw,             // [NPIX][16]
    int4* __restrict__ trec)            // [NPIX][16]  (mode-2 taps)
{
    __shared__ f32x4 Btap[PXB][16];
    const float tE = theta_p[0];
    const int b = blockIdx.x;
    const int pixblock = (b & 7) * (NBLK / 8) + (b >> 3);   // XCD swizzle
    const int p0 = pixblock * PXB;
    const int t  = threadIdx.x;

    // ---- 1A: tap geometry + patch base/mode; lanes = (2px group, tap) ----
    {
        const int g = t >> 4, sub = t & 15;
#pragma unroll
        for (int h = 0; h < 2; ++h) {
            const int pi = 2 * g + h;
            const int p  = p0 + pi;
            const Tap tp = tapgeom(p, sub, tE);
            const float x0f = (float)tp.x0, y0f = (float)tp.y0;
            float mnx = tp.inb ? x0f : 1e9f;
            float mny = tp.inb ? y0f : 1e9f;
#pragma unroll
            for (int off = 1; off < 16; off <<= 1) {
                mnx = fminf(mnx, __shfl_xor(mnx, off, 16));
                mny = fminf(mny, __shfl_xor(mny, off, 16));
            }
            const bool allout = (mnx > 5e8f);
            int viol = (tp.inb & ((x0f > mnx + 2.0f) | (y0f > mny + 2.0f))) ? 1 : 0;
#pragma unroll
            for (int off = 1; off < 16; off <<= 1)
                viol |= __shfl_xor(viol, off, 16);
            const float bxc = fminf(mnx, 252.0f);
            const float byc = fminf(mny, 252.0f);
            f32x4 rec;
            rec.x = tp.inb ? (x0f - bxc) : -1000.0f;
            rec.y = tp.inb ? (y0f - byc) : -1000.0f;
            rec.z = tp.wx;
            rec.w = tp.wy;
            Btap[pi][sub] = rec;
            if (viol) {                    // rare: store per-tap records
                int4 r4;
                r4.x = tp.inb ? ((tp.y0 * NSRC + tp.x0) * CSZ) : -1;
                r4.y = __float_as_int(tp.wx);
                r4.z = __float_as_int(tp.wy);
                r4.w = 0;
                trec[(size_t)p * 16 + sub] = r4;
            }
            if (sub == 0)
                tbase[p] = allout ? -1
                         : (viol ? -2 : (((int)byc) * NSRC + (int)bxc) * CSZ);
        }
    }
    __syncthreads();

    // ---- 1B: corner weights -> tw; lanes = (pixel, corner); 2 px/lane ----
    {
        const int sub = t & 15;
        const float cxf = (float)(sub & 3), cyf = (float)(sub >> 2);
#pragma unroll
        for (int h = 0; h < 2; ++h) {
            const int pi = (t >> 4) + 16 * h;
            float myw = 0.0f;
#pragma unroll
            for (int j = 0; j < 16; ++j) {
                const f32x4 r = Btap[pi][j];
                const float tx = cxf - r.x;
                const float ty = cyf - r.y;
                const float wxp = (tx == 0.0f) ? (1.0f - r.z)
                                : ((tx == 1.0f) ? r.z : 0.0f);
                const float wyp = (ty == 0.0f) ? (1.0f - r.w)
                                : ((ty == 1.0f) ? r.w : 0.0f);
                myw += wxp * wyp;
            }
            tw[(size_t)(p0 + pi) * 16 + sub] = myw * 0.0625f;
        }
    }
}

// ---------------- k3: pure table-driven gather (<=64 VGPR target) -----------
__global__ __launch_bounds__(256, 8) void cubelens_gather(
    const _Float16* __restrict__ ws,    // (256,256,64) fp16
    const int*  __restrict__ tbase,
    const float* __restrict__ tw,
    const int4* __restrict__ trec,
    float* __restrict__ out)            // (64,192,192) fp32
{
    __shared__ float smemO[CSZ][PXB + 1];
    const int b = blockIdx.x;
    const int pixblock = (b & 7) * (NBLK / 8) + (b >> 3);   // XCD swizzle
    const int p0 = pixblock * PXB;
    const int t  = threadIdx.x;
    const int pi2 = t >> 3, c8 = t & 7;
    const int p   = p0 + pi2;

    const int bm = tbase[p];
    float acc[8];
#pragma unroll
    for (int e = 0; e < 8; ++e) acc[e] = 0.0f;

    if (bm >= 0) {
        const float* __restrict__ wp = tw + (size_t)p * 16;
        const _Float16* __restrict__ base = ws + bm + c8 * 8;
#pragma unroll
        for (int half = 0; half < 2; ++half) {
            f16x8 v[8];
            f32x4 w0 = *(const f32x4*)(wp + half * 8);
            f32x4 w1 = *(const f32x4*)(wp + half * 8 + 4);
#pragma unroll
            for (int k = 0; k < 8; ++k) {
                const int cn = half * 8 + k;
                v[k] = *(const f16x8*)(base + ((cn >> 2) * NSRC + (cn & 3)) * CSZ);
            }
#pragma unroll
            for (int k = 0; k < 8; ++k) {
                const float w = (k < 4) ? w0[k] : w1[k - 4];
#pragma unroll
                for (int e = 0; e < 8; ++e)
                    acc[e] += w * (float)v[k][e];
            }
        }
    } else if (bm == -2) {
        // rare wide-span pixel: per-tap records
        const int4* __restrict__ tr = trec + (size_t)p * 16;
        for (int tap = 0; tap < 16; ++tap) {
            const int4 r4 = tr[tap];
            if (r4.x >= 0) {
                const float wx = __int_as_float(r4.y);
                const float wy = __int_as_float(r4.z);
                const _Float16* __restrict__ pp = ws + r4.x + c8 * 8;
                const f16x8 v00 = *(const f16x8*)(pp);
                const f16x8 v01 = *(const f16x8*)(pp + CSZ);
                const f16x8 v10 = *(const f16x8*)(pp + NSRC * CSZ);
                const f16x8 v11 = *(const f16x8*)(pp + NSRC * CSZ + CSZ);
                const float w00 = (1.0f - wy) * (1.0f - wx);
                const float w01 = (1.0f - wy) * wx;
                const float w10 = wy * (1.0f - wx);
                const float w11 = wy * wx;
#pragma unroll
                for (int e = 0; e < 8; ++e)
                    acc[e] += w00 * (float)v00[e] + w01 * (float)v01[e]
                            + w10 * (float)v10[e] + w11 * (float)v11[e];
            }
        }
#pragma unroll
        for (int e = 0; e < 8; ++e) acc[e] *= 0.0625f;
    }

#pragma unroll
    for (int e = 0; e < 8; ++e) smemO[c8 * 8 + e][pi2] = acc[e];
    __syncthreads();

    // epilogue: coalesced nontemporal f32x4 stores
    {
        const int c   = t >> 2;
        const int px8 = (t & 3) * 8;
        float* op = out + (size_t)c * NPIX + p0 + px8;
        f32x4 v0, v1;
        v0.x = smemO[c][px8 + 0]; v0.y = smemO[c][px8 + 1];
        v0.z = smemO[c][px8 + 2]; v0.w = smemO[c][px8 + 3];
        v1.x = smemO[c][px8 + 4]; v1.y = smemO[c][px8 + 5];
        v1.z = smemO[c][px8 + 6]; v1.w = smemO[c][px8 + 7];
        __builtin_nontemporal_store(v0, (f32x4*)op);
        __builtin_nontemporal_store(v1, (f32x4*)(op + 4));
    }
}

extern "C" void kernel_launch(void* const* d_in, const int* in_sizes, int n_in,
                              void* d_out, int out_size, void* d_ws, size_t ws_size,
                              hipStream_t stream) {
    const float* src   = (const float*)d_in[0];
    const float* theta = (const float*)d_in[1];
    float* out = (float*)d_out;

    if (ws_size >= (size_t)WS_TOTAL) {
        char* wsb = (char*)d_ws;
        _Float16* ws  = (_Float16*)wsb;
        int*   tbase  = (int*)(wsb + TB_OFF);
        float* tw     = (float*)(wsb + TW_OFF);
        int4*  trec   = (int4*)(wsb + TR_OFF);
        transpose_kernel<<<dim3(NTTILE), dim3(256), 0, stream>>>(src, ws);
        cubelens_weights<<<dim3(NBLK), dim3(256), 0, stream>>>(theta, tbase, tw, trec);
        cubelens_gather<<<dim3(NBLK), dim3(256), 0, stream>>>(ws, tbase, tw, trec, out);
    } else {
        cubelens_fallback<<<dim3(NPIX / 256, 8), dim3(256), 0, stream>>>(src, theta, out);
    }
}

// Round 19
// 29.528 us; speedup vs baseline: 1.4509x; 1.1535x over previous
//
#include <hip/hip_runtime.h>

// CubeLens: radial lens deflection + bilinear gather + 4x4 avg pool.
// C=64, NS=256, NL=192, UPS=4. Output (64,192,192) fp32.
//
// R19: DOUBLE THE WAVES. All mains since R6: 8 thr/px -> 4608 waves =
// 4.5/SIMD grid-wide (the decomposition, not VGPR/LDS, caps occupancy).
// This round: 16 thr/px (4 ch each, f16x4=8B loads; a pixel's 16 lanes
// still read one contiguous 128B block). 512-thr blocks, 9216 waves =
// 9/SIMD, ~32 waves/CU resident. Bonus: 1A/1B collapse to single pass
// (512 thr = 32px x 16 taps/corners exactly) -> half the geometry
// critical path. Same R14 machinery otherwise; phases stay wave-local
// (pixel group = 16 consecutive lanes).
//   k1: fp32->fp16 channel-last transpose, XCD swizzle (unchanged).

#define NSRC 256
#define NLENS 192
#define NPIX (NLENS * NLENS)     // 36864
#define CSZ  64
#define PXB  32                  // pixels per block (4 per wave now)
#define NBLK (NPIX / PXB)        // 1152, divisible by 8
#define NTTILE (NSRC * NSRC / 64)

typedef float    f32x4 __attribute__((ext_vector_type(4)));
typedef _Float16 f16x4 __attribute__((ext_vector_type(4)));
typedef _Float16 f16x8 __attribute__((ext_vector_type(8)));

// wave-local LDS sync: drain LDS ops, then stop compiler/scheduler motion
#define WAVE_SYNC() do {                                   \
    asm volatile("s_waitcnt lgkmcnt(0)" ::: "memory");     \
    __builtin_amdgcn_wave_barrier();                       \
    __builtin_amdgcn_sched_barrier(0);                     \
} while (0)

// ---------------- fallback (round-1 kernel, used only if ws too small) ------
__global__ __launch_bounds__(256) void cubelens_fallback(
    const float* __restrict__ src, const float* __restrict__ theta_p,
    float* __restrict__ out)
{
    const float tE = theta_p[0];
    const int pix = blockIdx.x * 256 + threadIdx.x;
    const int c0  = blockIdx.y * 8;
    const int lx  = pix % NLENS;
    const int ly  = pix / NLENS;
    float acc[8];
#pragma unroll
    for (int c = 0; c < 8; ++c) acc[c] = 0.0f;
    const float* __restrict__ srcg = src + (size_t)c0 * (NSRC * NSRC);
#pragma unroll
    for (int uy = 0; uy < 4; ++uy) {
        const float thy = ((float)(ly * 4 + uy) - 383.5f) * 0.01f;
#pragma unroll
        for (int ux = 0; ux < 4; ++ux) {
            const float thx = ((float)(lx * 4 + ux) - 383.5f) * 0.01f;
            const float r  = sqrtf(thx * thx + thy * thy) + 1e-8f;
            const float fx = (thx - (tE * thx) / r) / 0.02f + 127.5f;
            const float fy = (thy - (tE * thy) / r) / 0.02f + 127.5f;
            const bool inb = (fx >= 0.0f) & (fx <= 255.0f) &
                             (fy >= 0.0f) & (fy <= 255.0f);
            if (!inb) continue;
            int x0 = min(max((int)floorf(fx), 0), 254);
            int y0 = min(max((int)floorf(fy), 0), 254);
            const float wx = fminf(fmaxf(fx - (float)x0, 0.0f), 1.0f);
            const float wy = fminf(fmaxf(fy - (float)y0, 0.0f), 1.0f);
            const float w00 = (1.0f - wy) * (1.0f - wx);
            const float w01 = (1.0f - wy) * wx;
            const float w10 = wy * (1.0f - wx);
            const float w11 = wy * wx;
            const float* __restrict__ p = srcg + y0 * NSRC + x0;
#pragma unroll
            for (int c = 0; c < 8; ++c) {
                const float* __restrict__ pc = p + c * (NSRC * NSRC);
                acc[c] += w00 * pc[0] + w01 * pc[1]
                        + w10 * pc[NSRC] + w11 * pc[NSRC + 1];
            }
        }
    }
#pragma unroll
    for (int c = 0; c < 8; ++c)
        out[(size_t)(c0 + c) * NPIX + pix] = acc[c] * 0.0625f;
}

// ---------------- k1: transpose (c,p) fp32 -> (p,c) fp16, XCD swizzle -------
__global__ __launch_bounds__(256) void transpose_kernel(
    const float* __restrict__ src, _Float16* __restrict__ ws)
{
    __shared__ float tile[CSZ][65];
    const int b = blockIdx.x;
    const int tileid = (b & 7) * (NTTILE / 8) + (b >> 3);
    const int p0 = tileid * 64;
    const int t  = threadIdx.x;
    {
        const int crow = t >> 4;
        const int px4  = (t & 15) * 4;
#pragma unroll
        for (int i = 0; i < 4; ++i) {
            const int c = crow + 16 * i;
            const f32x4 v = __builtin_nontemporal_load(
                (const f32x4*)(src + (size_t)c * (NSRC * NSRC) + p0 + px4));
            tile[c][px4 + 0] = v.x; tile[c][px4 + 1] = v.y;
            tile[c][px4 + 2] = v.z; tile[c][px4 + 3] = v.w;
        }
    }
    __syncthreads();
    {
        const int c8 = (t & 7) * 8;
        const int pr = t >> 3;
#pragma unroll
        for (int i = 0; i < 2; ++i) {
            const int p = pr + 32 * i;
            f16x8 h;
#pragma unroll
            for (int k = 0; k < 8; ++k) h[k] = (_Float16)tile[c8 + k][p];
            *(f16x8*)(ws + (size_t)(p0 + p) * CSZ + c8) = h;
        }
    }
}

// ---------------- k2: lens gather, 16 threads/pixel -------------------------
struct Tap { int x0, y0; float wx, wy; bool inb; };

__device__ __forceinline__ Tap tapgeom(int p, int sub, float tE) {
    const int lx = p % NLENS, ly = p / NLENS;
    const float thy = ((float)(ly * 4 + (sub >> 2)) - 383.5f) * 0.01f;
    const float thx = ((float)(lx * 4 + (sub & 3))  - 383.5f) * 0.01f;
    const float r  = sqrtf(thx * thx + thy * thy) + 1e-8f;
    const float fx = (thx - (tE * thx) / r) / 0.02f + 127.5f;
    const float fy = (thy - (tE * thy) / r) / 0.02f + 127.5f;
    Tap tp;
    tp.inb = (fx >= 0.0f) & (fx <= 255.0f) & (fy >= 0.0f) & (fy <= 255.0f);
    tp.x0 = min(max((int)floorf(fx), 0), 254);
    tp.y0 = min(max((int)floorf(fy), 0), 254);
    tp.wx = fminf(fmaxf(fx - (float)tp.x0, 0.0f), 1.0f);
    tp.wy = fminf(fmaxf(fy - (float)tp.y0, 0.0f), 1.0f);
    return tp;
}

__global__ __launch_bounds__(512, 6) void cubelens_main(
    const _Float16* __restrict__ ws,    // (256,256,64) fp16
    const float* __restrict__ theta_p,
    float* __restrict__ out)            // (64,192,192) fp32
{
    __shared__ f32x4 Btap[PXB][16];     // 8 KB
    __shared__ float wpatch[PXB][16];   // 2 KB
    __shared__ int   gbase[PXB];
    __shared__ int   gmode[PXB];
    __shared__ float smemO[CSZ][PXB + 1];  // 8.4 KB

    const float tE = theta_p[0];
    const int b = blockIdx.x;
    const int pixblock = (b & 7) * (NBLK / 8) + (b >> 3);   // XCD swizzle
    const int p0 = pixblock * PXB;
    const int t  = threadIdx.x;         // 0..511
    const int pi  = t >> 4;             // pixel 0..31 (16-lane group)
    const int sub = t & 15;             // tap / corner / c4

    // ---- 1A: tap geometry, single pass (512 thr = 32 px x 16 taps) ----
    {
        const Tap tp = tapgeom(p0 + pi, sub, tE);
        const float x0f = (float)tp.x0, y0f = (float)tp.y0;
        float mnx = tp.inb ? x0f : 1e9f;
        float mny = tp.inb ? y0f : 1e9f;
#pragma unroll
        for (int off = 1; off < 16; off <<= 1) {
            mnx = fminf(mnx, __shfl_xor(mnx, off, 16));
            mny = fminf(mny, __shfl_xor(mny, off, 16));
        }
        const bool allout = (mnx > 5e8f);
        int viol = (tp.inb & ((x0f > mnx + 2.0f) | (y0f > mny + 2.0f))) ? 1 : 0;
#pragma unroll
        for (int off = 1; off < 16; off <<= 1)
            viol |= __shfl_xor(viol, off, 16);
        const float bxc = fminf(mnx, 252.0f);
        const float byc = fminf(mny, 252.0f);
        f32x4 rec;
        rec.x = tp.inb ? (x0f - bxc) : -1000.0f;
        rec.y = tp.inb ? (y0f - byc) : -1000.0f;
        rec.z = tp.wx;
        rec.w = tp.wy;
        Btap[pi][sub] = rec;
        if (sub == 0) {
            gbase[pi] = (((int)byc) * NSRC + (int)bxc) * CSZ;
            gmode[pi] = allout ? 0 : (viol ? 2 : 1);
        }
    }
    WAVE_SYNC();   // Btap/gbase/gmode for this wave's 4 pixels visible

    // ---- T14 issue-early: 16 f16x4 corner loads (c4 = sub) ----
    const int mode2 = gmode[pi];
    f16x4 v[16];
    if (mode2 == 1) {
        const _Float16* __restrict__ base = ws + gbase[pi] + sub * 4;
#pragma unroll
        for (int cn = 0; cn < 16; ++cn)
            v[cn] = *(const f16x4*)(base + ((cn >> 2) * NSRC + (cn & 3)) * CSZ);
    }

    // ---- 1B: corner weights while loads fly (single pass) ----
    {
        const float cxf = (float)(sub & 3), cyf = (float)(sub >> 2);
        float myw = 0.0f;
#pragma unroll
        for (int j = 0; j < 16; ++j) {
            const f32x4 r = Btap[pi][j];
            const float tx = cxf - r.x;
            const float ty = cyf - r.y;
            const float wxp = (tx == 0.0f) ? (1.0f - r.z)
                            : ((tx == 1.0f) ? r.z : 0.0f);
            const float wyp = (ty == 0.0f) ? (1.0f - r.w)
                            : ((ty == 1.0f) ? r.w : 0.0f);
            myw += wxp * wyp;
        }
        wpatch[pi][sub] = myw * 0.0625f;
    }
    WAVE_SYNC();   // wpatch for this wave's pixels visible

    // ---- phase 2: FMA on landed loads; thread = (pixel, c4) ----
    {
        float acc[4];
#pragma unroll
        for (int e = 0; e < 4; ++e) acc[e] = 0.0f;

        if (mode2 == 1) {
#pragma unroll
            for (int cn = 0; cn < 16; ++cn) {
                const float w = wpatch[pi][cn];
#pragma unroll
                for (int e = 0; e < 4; ++e)
                    acc[e] += w * (float)v[cn][e];     // v_fma_mix_f32
            }
        } else if (mode2 == 2) {
            for (int tap = 0; tap < 16; ++tap) {
                const Tap tp = tapgeom(p0 + pi, tap, tE);
                if (tp.inb) {
                    const _Float16* __restrict__ pp =
                        ws + (tp.y0 * NSRC + tp.x0) * CSZ + sub * 4;
                    const f16x4 v00 = *(const f16x4*)(pp);
                    const f16x4 v01 = *(const f16x4*)(pp + CSZ);
                    const f16x4 v10 = *(const f16x4*)(pp + NSRC * CSZ);
                    const f16x4 v11 = *(const f16x4*)(pp + NSRC * CSZ + CSZ);
                    const float w00 = (1.0f - tp.wy) * (1.0f - tp.wx);
                    const float w01 = (1.0f - tp.wy) * tp.wx;
                    const float w10 = tp.wy * (1.0f - tp.wx);
                    const float w11 = tp.wy * tp.wx;
#pragma unroll
                    for (int e = 0; e < 4; ++e)
                        acc[e] += w00 * (float)v00[e] + w01 * (float)v01[e]
                                + w10 * (float)v10[e] + w11 * (float)v11[e];
                }
            }
#pragma unroll
            for (int e = 0; e < 4; ++e) acc[e] *= 0.0625f;
        }

#pragma unroll
        for (int e = 0; e < 4; ++e) smemO[sub * 4 + e][pi] = acc[e];
    }
    __syncthreads();   // epilogue reads all 32 px across waves

    // ---- epilogue: coalesced nontemporal f32x4 stores (512 thr) ----
    {
        const int c   = t >> 3;          // 0..63
        const int px4 = (t & 7) * 4;     // 0..28
        float* op = out + (size_t)c * NPIX + p0 + px4;
        f32x4 v0;
        v0.x = smemO[c][px4 + 0]; v0.y = smemO[c][px4 + 1];
        v0.z = smemO[c][px4 + 2]; v0.w = smemO[c][px4 + 3];
        __builtin_nontemporal_store(v0, (f32x4*)op);
    }
}

extern "C" void kernel_launch(void* const* d_in, const int* in_sizes, int n_in,
                              void* d_out, int out_size, void* d_ws, size_t ws_size,
                              hipStream_t stream) {
    const float* src   = (const float*)d_in[0];
    const float* theta = (const float*)d_in[1];
    float* out = (float*)d_out;

    const size_t need = (size_t)CSZ * NSRC * NSRC * sizeof(_Float16);  // 8.4 MB
    if (ws_size >= need) {
        _Float16* ws = (_Float16*)d_ws;
        transpose_kernel<<<dim3(NTTILE), dim3(256), 0, stream>>>(src, ws);
        cubelens_main<<<dim3(NBLK), dim3(512), 0, stream>>>(ws, theta, out);
    } else {
        cubelens_fallback<<<dim3(NPIX / 256, 8), dim3(256), 0, stream>>>(src, theta, out);
    }
}